// Round 12
// baseline (315.000 us; speedup 1.0000x reference)
//
#include <hip/hip_runtime.h>
#include <math.h>

#define NB 2
#define NC 50
#define NCR 25
#define H0 48
#define W0 48
#define HW0 2304
#define LTOT 7470
#define LP 7552      // LTOT padded to 128
#define K225 225
#define KP 256       // 225 padded to 256
#define CD 450       // C*9
#define CDP 512      // padded to 128
#define NSPLIT 8
#define KCHUNK 960   // 7*960 + 832 = 7552; every chunk len %32 == 0

typedef _Float16 f16x8 __attribute__((ext_vector_type(8)));
typedef float f32x4 __attribute__((ext_vector_type(4)));

#define GLOAD_LDS16(gp, lp) __builtin_amdgcn_global_load_lds( \
    (const __attribute__((address_space(1))) void*)(gp),      \
    (__attribute__((address_space(3))) void*)(lp), 16, 0, 0)

__device__ __forceinline__ void decode_pix(int pix, int& s, int& off, int& d) {
  if (pix < 2304)      { s = 0; off = 0;    d = 48; }
  else if (pix < 4153) { s = 1; off = 2304; d = 43; }
  else if (pix < 5597) { s = 2; off = 4153; d = 38; }
  else if (pix < 6686) { s = 3; off = 5597; d = 33; }
  else                 { s = 4; off = 6686; d = 28; }
}

__device__ __forceinline__ float cubw(float t) {
  const float a = -0.75f;
  float at = fabsf(t);
  float w1 = ((a + 2.f) * at - (a + 3.f)) * at * at + 1.f;
  float w2 = (((at - 5.f) * at + 8.f) * at - 4.f) * a;
  return at <= 1.f ? w1 : (at < 2.f ? w2 : 0.f);
}

__global__ void k_conv1x1(const float* __restrict__ in, const float* __restrict__ Wt,
                          const float* __restrict__ bias, const float* __restrict__ slope,
                          float* __restrict__ out, int Cin, int O, int P) {
  int t = blockIdx.x * blockDim.x + threadIdx.x;
  int total = NB * O * P;
  if (t >= total) return;
  int pix = t % P;
  int o = (t / P) % O;
  int b = t / (P * O);
  float acc = bias[o];
  const float* ip = in + (size_t)b * Cin * P + pix;
  const float* wr = Wt + o * Cin;
  for (int c = 0; c < Cin; ++c) acc = fmaf(wr[c], ip[(size_t)c * P], acc);
  float a = slope[0];
  out[t] = acc >= 0.f ? acc : a * acc;
}

// fused: base (50 ch, Wa) and m (25 ch, Wm) from refs, one pass
__global__ void k_conv_bm(const float* __restrict__ refs,
                          const float* __restrict__ Wa, const float* __restrict__ ba,
                          const float* __restrict__ aa,
                          const float* __restrict__ Wm, const float* __restrict__ bm,
                          const float* __restrict__ am,
                          float* __restrict__ base, float* __restrict__ m) {
  int t = blockIdx.x * blockDim.x + threadIdx.x;
  int total = NB * (NC + NCR) * LTOT;
  if (t >= total) return;
  int pix = t % LTOT;
  int o = (t / LTOT) % (NC + NCR);
  int b = t / (LTOT * (NC + NCR));
  const float* ip = refs + (size_t)b * NC * LTOT + pix;
  const float* wr;
  float acc, a;
  float* dst;
  if (o < NC) {
    wr = Wa + o * NC; acc = ba[o]; a = aa[0];
    dst = base + ((size_t)b * NC + o) * LTOT + pix;
  } else {
    int o2 = o - NC;
    wr = Wm + o2 * NC; acc = bm[o2]; a = am[0];
    dst = m + ((size_t)b * NCR + o2) * LTOT + pix;
  }
  for (int c = 0; c < NC; ++c) acc = fmaf(wr[c], ip[(size_t)c * LTOT], acc);
  *dst = acc >= 0.f ? acc : a * acc;
}

__global__ void k_build_refs(const float* __restrict__ x, float* __restrict__ refs) {
  int t = blockIdx.x * blockDim.x + threadIdx.x;
  int total = NB * NC * LTOT;
  if (t >= total) return;
  int pix = t % LTOT;
  int c = (t / LTOT) % NC;
  int b = t / (LTOT * NC);
  int s, off, d;
  decode_pix(pix, s, off, d);
  float v;
  const float* xb = x + ((size_t)b * NC + c) * HW0;
  if (s == 0) {
    v = xb[pix];
  } else {
    int rem = pix - off;
    int oy = rem / d, ox = rem % d;
    float scale = 47.f / (float)(d - 1);
    float sy = oy * scale, sx = ox * scale;
    float fy0 = floorf(sy), fx0 = floorf(sx);
    int iy = (int)fy0, ix = (int)fx0;
    float fy = sy - fy0, fx = sx - fx0;
    float wy[4], wx[4];
#pragma unroll
    for (int dd = 0; dd < 4; ++dd) {
      wy[dd] = cubw(fy - (float)(dd - 1));
      wx[dd] = cubw(fx - (float)(dd - 1));
    }
    float acc = 0.f;
#pragma unroll
    for (int p = 0; p < 4; ++p) {
      int yy = min(max(iy + p - 1, 0), 47);
      float rowacc = 0.f;
#pragma unroll
      for (int q = 0; q < 4; ++q) {
        int xx = min(max(ix + q - 1, 0), 47);
        rowacc = fmaf(wx[q], xb[yy * 48 + xx], rowacc);
      }
      acc = fmaf(wy[p], rowacc, acc);
    }
    v = acc;
  }
  refs[t] = v;
}

__global__ void k_build_xq(const float* __restrict__ mb, _Float16* __restrict__ xq) {
  int bp = blockIdx.x;
  int b = bp / HW0, p = bp % HW0;
  int i = p / W0, j = p % W0;
  int k = threadIdx.x;
  float v = 0.f;
  if (k < K225) {
    int c = k / 9, r = k % 9, di = r / 3, dj = r % 3;
    int yy = i + di - 1, xx = j + dj - 1;
    if (yy >= 0 && yy < H0 && xx >= 0 && xx < W0)
      v = mb[((size_t)b * NCR + c) * HW0 + yy * W0 + xx];
  }
  xq[(size_t)bp * KP + k] = (_Float16)v;
}

__global__ void k_build_wn(const float* __restrict__ m, _Float16* __restrict__ wn) {
  __shared__ float red[256];
  int bl = blockIdx.x;
  int b = bl / LP, l = bl % LP;
  int k = threadIdx.x;
  if (l >= LTOT) {
    wn[(size_t)bl * KP + k] = (_Float16)0.f;
    return;
  }
  int s, off, d;
  decode_pix(l, s, off, d);
  int rem = l - off;
  int y = rem / d, x = rem % d;
  float v = 0.f;
  if (k < K225) {
    int c = k / 9, r = k % 9, di = r / 3, dj = r % 3;
    int yy = y + di - 1, xx = x + dj - 1;
    if (yy >= 0 && yy < d && xx >= 0 && xx < d)
      v = m[((size_t)b * NCR + c) * LTOT + off + yy * d + xx];
  }
  red[k] = v * v;
  __syncthreads();
  for (int st = 128; st > 0; st >>= 1) {
    if (k < st) red[k] += red[k + st];
    __syncthreads();
  }
  float norm = sqrtf(red[0]);
  float sc = 10.f / fmaxf(norm, 1e-4f);
  wn[(size_t)bl * KP + k] = (_Float16)(v * sc);
}

__global__ void k_build_brawT(const float* __restrict__ base, _Float16* __restrict__ BT) {
  int t = blockIdx.x * blockDim.x + threadIdx.x;
  int total = NB * CDP * LP;
  if (t >= total) return;
  int l = t % LP;
  int cd = (t / LP) % CDP;
  int b = t / (LP * CDP);
  float v = 0.f;
  if (cd < CD && l < LTOT) {
    int s, off, d;
    decode_pix(l, s, off, d);
    int rem = l - off;
    int y = rem / d, x = rem % d;
    int c = cd / 9, r = cd % 9, di = r / 3, dj = r % 3;
    int yy = y + di - 1, xx = x + dj - 1;
    if (yy >= 0 && yy < d && xx >= 0 && xx < d)
      v = 0.25f * base[((size_t)b * NC + c) * LTOT + off + yy * d + xx];
  }
  BT[t] = (_Float16)v;
}

// GEMM1: C[m,n] = sum_k A[m,k]*B[n,k], 128x128 tile, 4 waves, fp16 out.
// Double-buffered LDS: stage k+1 before computing k (overlap global latency).
__global__ __launch_bounds__(256) void k_gemm_nt_f16(
    const _Float16* __restrict__ A, const _Float16* __restrict__ Bm,
    _Float16* __restrict__ Cm, int K, int lda, int ldb, int ldc,
    long long sA, long long sB, long long sC) {
  __shared__ _Float16 As[2][128 * 32];
  __shared__ _Float16 Bs[2][128 * 32];
  const _Float16* Ab = A + blockIdx.z * sA;
  const _Float16* Bb = Bm + blockIdx.z * sB;
  _Float16* Cb = Cm + blockIdx.z * sC;
  int m0 = blockIdx.y * 128, n0 = blockIdx.x * 128;
  int t = threadIdx.x;
  int lane = t & 63, wid = t >> 6;
  int wr = wid >> 1, wc = wid & 1;
  int r = t >> 2, c4 = t & 3;      // staging coords: 256 threads x 2 chunks
  f32x4 acc[4][4] = {};

#define G1_STAGE(buf, k0)                                                        \
  {                                                                              \
    GLOAD_LDS16(Ab + (size_t)(m0 + r) * lda + (k0) + c4 * 8,                     \
                As[buf] + (size_t)t * 8);                                        \
    GLOAD_LDS16(Ab + (size_t)(m0 + 64 + r) * lda + (k0) + c4 * 8,                \
                As[buf] + (size_t)(256 + t) * 8);                                \
    GLOAD_LDS16(Bb + (size_t)(n0 + r) * ldb + (k0) + c4 * 8,                     \
                Bs[buf] + (size_t)t * 8);                                        \
    GLOAD_LDS16(Bb + (size_t)(n0 + 64 + r) * ldb + (k0) + c4 * 8,                \
                Bs[buf] + (size_t)(256 + t) * 8);                                \
  }

  G1_STAGE(0, 0);
  __syncthreads();
  int cur = 0;
  for (int k0 = 0; k0 < K; k0 += 32) {
    if (k0 + 32 < K) G1_STAGE(cur ^ 1, k0 + 32);
    int rla = (wr * 64 + (lane & 15)) * 32 + (lane >> 4) * 8;
    int rlb = (wc * 64 + (lane & 15)) * 32 + (lane >> 4) * 8;
    f16x8 af[4], bf[4];
#pragma unroll
    for (int mi = 0; mi < 4; ++mi) af[mi] = *(const f16x8*)&As[cur][rla + mi * 16 * 32];
#pragma unroll
    for (int ni = 0; ni < 4; ++ni) bf[ni] = *(const f16x8*)&Bs[cur][rlb + ni * 16 * 32];
#pragma unroll
    for (int mi = 0; mi < 4; ++mi)
#pragma unroll
      for (int ni = 0; ni < 4; ++ni)
        acc[mi][ni] = __builtin_amdgcn_mfma_f32_16x16x32_f16(af[mi], bf[ni], acc[mi][ni], 0, 0, 0);
    __syncthreads();
    cur ^= 1;
  }
  int col0 = lane & 15;
  int row0 = (lane >> 4) * 4;
#pragma unroll
  for (int mi = 0; mi < 4; ++mi) {
#pragma unroll
    for (int ni = 0; ni < 4; ++ni) {
      int n = n0 + wc * 64 + ni * 16 + col0;
#pragma unroll
      for (int rr = 0; rr < 4; ++rr) {
        int mrow = m0 + wr * 64 + mi * 16 + row0 + rr;
        Cb[(size_t)mrow * ldc + n] = (_Float16)acc[mi][ni][rr];
      }
    }
  }
}

// GEMM2: split-K, 128x256 tile, 8 waves (512 thr), fp16 partials, dbuf LDS.
__global__ __launch_bounds__(512) void k_gemm2(
    const _Float16* __restrict__ A, const _Float16* __restrict__ Bm,
    _Float16* __restrict__ Cm, int lda, int ldb, int ldc,
    long long sA, long long sB, long long sC) {
  __shared__ _Float16 As[2][128 * 32];
  __shared__ _Float16 Bs[2][256 * 32];
  int z = blockIdx.z;
  int b = z / NSPLIT, s = z % NSPLIT;
  int kbeg = s * KCHUNK;
  int klen = min(KCHUNK, LP - kbeg);
  const _Float16* Ab = A + b * sA + (size_t)kbeg;
  const _Float16* Bb = Bm + b * sB + (size_t)kbeg;
  _Float16* Cb = Cm + z * sC;
  int m0 = blockIdx.y * 128, n0 = blockIdx.x * 256;
  int t = threadIdx.x;
  int lane = t & 63, wid = t >> 6;
  int wr = wid >> 2, wc = wid & 3;   // 2 x 4 wave grid, each wave 64x64
  int r = t >> 2, c4 = t & 3;        // staging: 512 threads

#define G2_STAGE(buf, k0)                                                        \
  {                                                                              \
    GLOAD_LDS16(Ab + (size_t)(m0 + r) * lda + (k0) + c4 * 8,                     \
                As[buf] + (size_t)t * 8);                                        \
    GLOAD_LDS16(Bb + (size_t)(n0 + r) * ldb + (k0) + c4 * 8,                     \
                Bs[buf] + (size_t)t * 8);                                        \
    GLOAD_LDS16(Bb + (size_t)(n0 + 128 + r) * ldb + (k0) + c4 * 8,               \
                Bs[buf] + (size_t)(512 + t) * 8);                                \
  }

  f32x4 acc[4][4] = {};
  G2_STAGE(0, 0);
  __syncthreads();
  int cur = 0;
  for (int k0 = 0; k0 < klen; k0 += 32) {
    if (k0 + 32 < klen) G2_STAGE(cur ^ 1, k0 + 32);
    int rla = (wr * 64 + (lane & 15)) * 32 + (lane >> 4) * 8;
    int rlb = (wc * 64 + (lane & 15)) * 32 + (lane >> 4) * 8;
    f16x8 af[4], bf[4];
#pragma unroll
    for (int mi = 0; mi < 4; ++mi) af[mi] = *(const f16x8*)&As[cur][rla + mi * 16 * 32];
#pragma unroll
    for (int ni = 0; ni < 4; ++ni) bf[ni] = *(const f16x8*)&Bs[cur][rlb + ni * 16 * 32];
#pragma unroll
    for (int mi = 0; mi < 4; ++mi)
#pragma unroll
      for (int ni = 0; ni < 4; ++ni)
        acc[mi][ni] = __builtin_amdgcn_mfma_f32_16x16x32_f16(af[mi], bf[ni], acc[mi][ni], 0, 0, 0);
    __syncthreads();
    cur ^= 1;
  }
  int col0 = lane & 15;
  int row0 = (lane >> 4) * 4;
#pragma unroll
  for (int mi = 0; mi < 4; ++mi) {
#pragma unroll
    for (int ni = 0; ni < 4; ++ni) {
      int n = n0 + wc * 64 + ni * 16 + col0;
#pragma unroll
      for (int rr = 0; rr < 4; ++rr) {
        int mrow = m0 + wr * 64 + mi * 16 + row0 + rr;
        Cb[(size_t)mrow * ldc + n] = (_Float16)acc[mi][ni][rr];
      }
    }
  }
}

// fp16 in/out, in-place softmax over l<LTOT of each LP row; pad cols -> 0
__global__ void k_softmax16(_Float16* __restrict__ S) {
  __shared__ float buf[LTOT];
  __shared__ float red[256];
  size_t row = blockIdx.x;
  _Float16* r = S + row * LP;
  f16x8* r8 = (f16x8*)r;
  int tid = threadIdx.x;
  float mx = -1e30f;
  for (int ch = tid; ch < LP / 8; ch += 256) {
    f16x8 v = r8[ch];
    int base = ch * 8;
#pragma unroll
    for (int j = 0; j < 8; ++j) {
      int l = base + j;
      if (l < LTOT) {
        float f = (float)v[j];
        buf[l] = f;
        mx = fmaxf(mx, f);
      }
    }
  }
  red[tid] = mx;
  __syncthreads();
  for (int st = 128; st > 0; st >>= 1) {
    if (tid < st) red[tid] = fmaxf(red[tid], red[tid + st]);
    __syncthreads();
  }
  mx = red[0];
  __syncthreads();
  float sm = 0.f;
  for (int i = tid; i < LTOT; i += 256) {
    float e = __expf(buf[i] - mx);
    buf[i] = e;
    sm += e;
  }
  red[tid] = sm;
  __syncthreads();
  for (int st = 128; st > 0; st >>= 1) {
    if (tid < st) red[tid] += red[tid + st];
    __syncthreads();
  }
  float inv = 1.f / red[0];
  __syncthreads();
  for (int ch = tid; ch < LP / 8; ch += 256) {
    int base = ch * 8;
    f16x8 o;
#pragma unroll
    for (int j = 0; j < 8; ++j) {
      int l = base + j;
      o[j] = (l < LTOT) ? (_Float16)(buf[l] * inv) : (_Float16)0.f;
    }
    r8[ch] = o;
  }
}

// coalesced: cd fastest. G[b, p0+p, cd<450] = sum_s fp16 Gp[(b*NSPLIT+s), p, cd]
__global__ void k_reduceG(const _Float16* __restrict__ Gp, float* __restrict__ G,
                          int pc, int p0) {
  int t = blockIdx.x * blockDim.x + threadIdx.x;
  int total = NB * pc * CD;
  if (t >= total) return;
  int cd = t % CD;
  int p = (t / CD) % pc;
  int b = t / (CD * pc);
  float acc = 0.f;
#pragma unroll
  for (int s = 0; s < NSPLIT; ++s)
    acc += (float)Gp[(((size_t)(b * NSPLIT + s) * pc) + p) * CDP + cd];
  G[((size_t)b * HW0 + p0 + p) * CD + cd] = acc;
}

__global__ void k_final(const float* __restrict__ G, const float* __restrict__ x,
                        float* __restrict__ out) {
  int t = blockIdx.x * blockDim.x + threadIdx.x;
  int total = NB * NC * HW0;
  if (t >= total) return;
  int p = t % HW0;
  int c = (t / HW0) % NC;
  int b = t / (HW0 * NC);
  int i = p / W0, j = p % W0;
  float sum = 0.f;
#pragma unroll
  for (int kh = 0; kh < 3; ++kh) {
    int pi = i - kh + 1;
    if (pi < 0 || pi >= H0) continue;
#pragma unroll
    for (int kw = 0; kw < 3; ++kw) {
      int pj = j - kw + 1;
      if (pj < 0 || pj >= W0) continue;
      sum += G[((size_t)b * HW0 + pi * W0 + pj) * CD + c * 9 + kh * 3 + kw];
    }
  }
  out[t] = sum + x[t];
}

static inline size_t rup(size_t x) { return (x + 255) & ~(size_t)255; }

extern "C" void kernel_launch(void* const* d_in, const int* in_sizes, int n_in,
                              void* d_out, int out_size, void* d_ws, size_t ws_size,
                              hipStream_t stream) {
  const float* x   = (const float*)d_in[0];
  const float* Wmb = (const float*)d_in[1];
  const float* bmb = (const float*)d_in[2];
  const float* amb = (const float*)d_in[3];
  const float* Wm  = (const float*)d_in[4];
  const float* bm  = (const float*)d_in[5];
  const float* am  = (const float*)d_in[6];
  const float* Wa  = (const float*)d_in[7];
  const float* ba  = (const float*)d_in[8];
  const float* aa  = (const float*)d_in[9];
  float* out = (float*)d_out;
  char* ws = (char*)d_ws;

  size_t off = 0;
  float* mb    = (float*)(ws + off); off = rup(off + sizeof(float) * NB * NCR * HW0);
  float* refs  = (float*)(ws + off); off = rup(off + sizeof(float) * NB * NC * LTOT);
  float* base  = (float*)(ws + off); off = rup(off + sizeof(float) * NB * NC * LTOT);
  float* m     = (float*)(ws + off); off = rup(off + sizeof(float) * NB * NCR * LTOT);
  _Float16* xq16 = (_Float16*)(ws + off); off = rup(off + sizeof(_Float16) * NB * HW0 * KP);
  _Float16* wn16 = (_Float16*)(ws + off); off = rup(off + sizeof(_Float16) * (size_t)NB * LP * KP);
  _Float16* bt16 = (_Float16*)(ws + off); off = rup(off + sizeof(_Float16) * (size_t)NB * CDP * LP);
  float* G     = (float*)(ws + off); off = rup(off + sizeof(float) * NB * HW0 * CD);

  // per-chunk: scores/attn fp16 [NB][pc][LP] + Gp fp16 [NB*NSPLIT][pc][CDP]
  int pc = HW0;
  {
    size_t avail = (ws_size > off) ? ws_size - off - 1024 : 0;
    size_t per = (size_t)NB * (LP * 2 + NSPLIT * CDP * 2);
    while (pc > 128 && (size_t)pc * per > avail) {
      if (pc == HW0) pc = 1152;
      else if (pc == 1152) pc = 768;
      else if (pc == 768) pc = 384;
      else pc = 128;
    }
  }
  _Float16* scbuf16 = (_Float16*)(ws + off); off = rup(off + sizeof(_Float16) * (size_t)NB * pc * LP);
  _Float16* Gp = (_Float16*)(ws + off);

  const int th = 256;
  k_conv1x1<<<(NB * NCR * HW0 + th - 1) / th, th, 0, stream>>>(x, Wmb, bmb, amb, mb, NC, NCR, HW0);
  k_build_refs<<<(NB * NC * LTOT + th - 1) / th, th, 0, stream>>>(x, refs);
  k_conv_bm<<<(NB * (NC + NCR) * LTOT + th - 1) / th, th, 0, stream>>>(
      refs, Wa, ba, aa, Wm, bm, am, base, m);
  k_build_xq<<<NB * HW0, 256, 0, stream>>>(mb, xq16);
  k_build_wn<<<NB * LP, 256, 0, stream>>>(m, wn16);
  k_build_brawT<<<(NB * CDP * LP + th - 1) / th, th, 0, stream>>>(base, bt16);

  for (int p0 = 0; p0 < HW0; p0 += pc) {
    // scores fp16: [b, p, l] = xq . wn
    dim3 g1(LP / 128, pc / 128, NB);
    k_gemm_nt_f16<<<g1, 256, 0, stream>>>(
        xq16 + (size_t)p0 * KP, wn16, scbuf16,
        KP, KP, KP, LP,
        (long long)HW0 * KP, (long long)LP * KP, (long long)pc * LP);
    // softmax in place (fp16 -> fp16 attn)
    k_softmax16<<<NB * pc, 256, 0, stream>>>(scbuf16);
    // Gp[(b,s), p, cd] = attn(chunk s) . BrawT(chunk s); 128x256 tile, 8 waves
    dim3 g2(CDP / 256, pc / 128, NB * NSPLIT);
    k_gemm2<<<g2, 512, 0, stream>>>(
        scbuf16, bt16, Gp,
        LP, LP, CDP,
        (long long)pc * LP, (long long)CDP * LP, (long long)pc * CDP);
    // coalesced split-reduce into G
    k_reduceG<<<(NB * pc * CD + th - 1) / th, th, 0, stream>>>(Gp, G, pc, p0);
  }
  k_final<<<(NB * NC * HW0 + th - 1) / th, th, 0, stream>>>(G, x, out);
}

// Round 13
// 302.704 us; speedup vs baseline: 1.0406x; 1.0406x over previous
//
#include <hip/hip_runtime.h>
#include <math.h>

#define NB 2
#define NC 50
#define NCR 25
#define H0 48
#define W0 48
#define HW0 2304
#define LTOT 7470
#define LP 7552      // LTOT padded to 128
#define K225 225
#define KP 256       // 225 padded to 256
#define CD 450       // C*9
#define CDP 512      // padded to 128
#define NSPLIT 8
#define KCHUNK 960   // 7*960 + 832 = 7552; both 960 and 832 are %64 == 0

typedef _Float16 f16x8 __attribute__((ext_vector_type(8)));
typedef float f32x4 __attribute__((ext_vector_type(4)));

#define GLOAD_LDS16(gp, lp) __builtin_amdgcn_global_load_lds( \
    (const __attribute__((address_space(1))) void*)(gp),      \
    (__attribute__((address_space(3))) void*)(lp), 16, 0, 0)

__device__ __forceinline__ void decode_pix(int pix, int& s, int& off, int& d) {
  if (pix < 2304)      { s = 0; off = 0;    d = 48; }
  else if (pix < 4153) { s = 1; off = 2304; d = 43; }
  else if (pix < 5597) { s = 2; off = 4153; d = 38; }
  else if (pix < 6686) { s = 3; off = 5597; d = 33; }
  else                 { s = 4; off = 6686; d = 28; }
}

__device__ __forceinline__ float cubw(float t) {
  const float a = -0.75f;
  float at = fabsf(t);
  float w1 = ((a + 2.f) * at - (a + 3.f)) * at * at + 1.f;
  float w2 = (((at - 5.f) * at + 8.f) * at - 4.f) * a;
  return at <= 1.f ? w1 : (at < 2.f ? w2 : 0.f);
}

__global__ void k_conv1x1(const float* __restrict__ in, const float* __restrict__ Wt,
                          const float* __restrict__ bias, const float* __restrict__ slope,
                          float* __restrict__ out, int Cin, int O, int P) {
  int t = blockIdx.x * blockDim.x + threadIdx.x;
  int total = NB * O * P;
  if (t >= total) return;
  int pix = t % P;
  int o = (t / P) % O;
  int b = t / (P * O);
  float acc = bias[o];
  const float* ip = in + (size_t)b * Cin * P + pix;
  const float* wr = Wt + o * Cin;
  for (int c = 0; c < Cin; ++c) acc = fmaf(wr[c], ip[(size_t)c * P], acc);
  float a = slope[0];
  out[t] = acc >= 0.f ? acc : a * acc;
}

// fused: base (50 ch, Wa) and m (25 ch, Wm) from refs, one pass
__global__ void k_conv_bm(const float* __restrict__ refs,
                          const float* __restrict__ Wa, const float* __restrict__ ba,
                          const float* __restrict__ aa,
                          const float* __restrict__ Wm, const float* __restrict__ bm,
                          const float* __restrict__ am,
                          float* __restrict__ base, float* __restrict__ m) {
  int t = blockIdx.x * blockDim.x + threadIdx.x;
  int total = NB * (NC + NCR) * LTOT;
  if (t >= total) return;
  int pix = t % LTOT;
  int o = (t / LTOT) % (NC + NCR);
  int b = t / (LTOT * (NC + NCR));
  const float* ip = refs + (size_t)b * NC * LTOT + pix;
  const float* wr;
  float acc, a;
  float* dst;
  if (o < NC) {
    wr = Wa + o * NC; acc = ba[o]; a = aa[0];
    dst = base + ((size_t)b * NC + o) * LTOT + pix;
  } else {
    int o2 = o - NC;
    wr = Wm + o2 * NC; acc = bm[o2]; a = am[0];
    dst = m + ((size_t)b * NCR + o2) * LTOT + pix;
  }
  for (int c = 0; c < NC; ++c) acc = fmaf(wr[c], ip[(size_t)c * LTOT], acc);
  *dst = acc >= 0.f ? acc : a * acc;
}

__global__ void k_build_refs(const float* __restrict__ x, float* __restrict__ refs) {
  int t = blockIdx.x * blockDim.x + threadIdx.x;
  int total = NB * NC * LTOT;
  if (t >= total) return;
  int pix = t % LTOT;
  int c = (t / LTOT) % NC;
  int b = t / (LTOT * NC);
  int s, off, d;
  decode_pix(pix, s, off, d);
  float v;
  const float* xb = x + ((size_t)b * NC + c) * HW0;
  if (s == 0) {
    v = xb[pix];
  } else {
    int rem = pix - off;
    int oy = rem / d, ox = rem % d;
    float scale = 47.f / (float)(d - 1);
    float sy = oy * scale, sx = ox * scale;
    float fy0 = floorf(sy), fx0 = floorf(sx);
    int iy = (int)fy0, ix = (int)fx0;
    float fy = sy - fy0, fx = sx - fx0;
    float wy[4], wx[4];
#pragma unroll
    for (int dd = 0; dd < 4; ++dd) {
      wy[dd] = cubw(fy - (float)(dd - 1));
      wx[dd] = cubw(fx - (float)(dd - 1));
    }
    float acc = 0.f;
#pragma unroll
    for (int p = 0; p < 4; ++p) {
      int yy = min(max(iy + p - 1, 0), 47);
      float rowacc = 0.f;
#pragma unroll
      for (int q = 0; q < 4; ++q) {
        int xx = min(max(ix + q - 1, 0), 47);
        rowacc = fmaf(wx[q], xb[yy * 48 + xx], rowacc);
      }
      acc = fmaf(wy[p], rowacc, acc);
    }
    v = acc;
  }
  refs[t] = v;
}

__global__ void k_build_xq(const float* __restrict__ mb, _Float16* __restrict__ xq) {
  int bp = blockIdx.x;
  int b = bp / HW0, p = bp % HW0;
  int i = p / W0, j = p % W0;
  int k = threadIdx.x;
  float v = 0.f;
  if (k < K225) {
    int c = k / 9, r = k % 9, di = r / 3, dj = r % 3;
    int yy = i + di - 1, xx = j + dj - 1;
    if (yy >= 0 && yy < H0 && xx >= 0 && xx < W0)
      v = mb[((size_t)b * NCR + c) * HW0 + yy * W0 + xx];
  }
  xq[(size_t)bp * KP + k] = (_Float16)v;
}

// one 64-lane wave per row (4 waves/block); shfl reduce, no barriers
__global__ void k_build_wn(const float* __restrict__ m, _Float16* __restrict__ wn) {
  int gw = blockIdx.x * 4 + (threadIdx.x >> 6);
  int lane = threadIdx.x & 63;
  int b = gw / LP, l = gw % LP;
  float v[4] = {0.f, 0.f, 0.f, 0.f};
  float ss = 0.f;
  if (l < LTOT) {
    int s, off, d;
    decode_pix(l, s, off, d);
    int rem = l - off;
    int y = rem / d, x = rem % d;
#pragma unroll
    for (int j = 0; j < 4; ++j) {
      int k = lane + 64 * j;
      if (k < K225) {
        int c = k / 9, r = k % 9, di = r / 3, dj = r % 3;
        int yy = y + di - 1, xx = x + dj - 1;
        if (yy >= 0 && yy < d && xx >= 0 && xx < d)
          v[j] = m[((size_t)b * NCR + c) * LTOT + off + yy * d + xx];
      }
      ss = fmaf(v[j], v[j], ss);
    }
  }
#pragma unroll
  for (int o = 1; o < 64; o <<= 1) ss += __shfl_xor(ss, o);
  float sc = 10.f / fmaxf(sqrtf(ss), 1e-4f);
#pragma unroll
  for (int j = 0; j < 4; ++j) {
    int k = lane + 64 * j;
    wn[(size_t)gw * KP + k] = (l < LTOT) ? (_Float16)(v[j] * sc) : (_Float16)0.f;
  }
}

__global__ void k_build_brawT(const float* __restrict__ base, _Float16* __restrict__ BT) {
  int t = blockIdx.x * blockDim.x + threadIdx.x;
  int total = NB * CDP * LP;
  if (t >= total) return;
  int l = t % LP;
  int cd = (t / LP) % CDP;
  int b = t / (LP * CDP);
  float v = 0.f;
  if (cd < CD && l < LTOT) {
    int s, off, d;
    decode_pix(l, s, off, d);
    int rem = l - off;
    int y = rem / d, x = rem % d;
    int c = cd / 9, r = cd % 9, di = r / 3, dj = r % 3;
    int yy = y + di - 1, xx = x + dj - 1;
    if (yy >= 0 && yy < d && xx >= 0 && xx < d)
      v = 0.25f * base[((size_t)b * NC + c) * LTOT + off + yy * d + xx];
  }
  BT[t] = (_Float16)v;
}

// GEMM1: C[m,n] = sum_k A[m,k]*B[n,k], 128x128 tile, 4 waves, fp16 out.
// BK=64: two K=32 subtiles per barrier round (halved barrier count).
__global__ __launch_bounds__(256) void k_gemm_nt_f16(
    const _Float16* __restrict__ A, const _Float16* __restrict__ Bm,
    _Float16* __restrict__ Cm, int K, int lda, int ldb, int ldc,
    long long sA, long long sB, long long sC) {
  __shared__ _Float16 As[2][128 * 32];   // [khalf][row*32+col]
  __shared__ _Float16 Bs[2][128 * 32];
  const _Float16* Ab = A + blockIdx.z * sA;
  const _Float16* Bb = Bm + blockIdx.z * sB;
  _Float16* Cb = Cm + blockIdx.z * sC;
  int m0 = blockIdx.y * 128, n0 = blockIdx.x * 128;
  int t = threadIdx.x;
  int lane = t & 63, wid = t >> 6;
  int wr = wid >> 1, wc = wid & 1;
  f32x4 acc[4][4] = {};
  for (int k0 = 0; k0 < K; k0 += 64) {
#pragma unroll
    for (int h = 0; h < 2; ++h) {
#pragma unroll
      for (int i = 0; i < 2; ++i) {
        int e = i * 256 + t;
        int r = e >> 2, c = e & 3;
        GLOAD_LDS16(Ab + (size_t)(m0 + r) * lda + k0 + h * 32 + c * 8, As[h] + (size_t)e * 8);
        GLOAD_LDS16(Bb + (size_t)(n0 + r) * ldb + k0 + h * 32 + c * 8, Bs[h] + (size_t)e * 8);
      }
    }
    __syncthreads();
    int rla = (wr * 64 + (lane & 15)) * 32 + (lane >> 4) * 8;
    int rlb = (wc * 64 + (lane & 15)) * 32 + (lane >> 4) * 8;
#pragma unroll
    for (int h = 0; h < 2; ++h) {
      f16x8 af[4], bf[4];
#pragma unroll
      for (int mi = 0; mi < 4; ++mi) af[mi] = *(const f16x8*)&As[h][rla + mi * 16 * 32];
#pragma unroll
      for (int ni = 0; ni < 4; ++ni) bf[ni] = *(const f16x8*)&Bs[h][rlb + ni * 16 * 32];
#pragma unroll
      for (int mi = 0; mi < 4; ++mi)
#pragma unroll
        for (int ni = 0; ni < 4; ++ni)
          acc[mi][ni] = __builtin_amdgcn_mfma_f32_16x16x32_f16(af[mi], bf[ni], acc[mi][ni], 0, 0, 0);
    }
    __syncthreads();
  }
  int col0 = lane & 15;
  int row0 = (lane >> 4) * 4;
#pragma unroll
  for (int mi = 0; mi < 4; ++mi) {
#pragma unroll
    for (int ni = 0; ni < 4; ++ni) {
      int n = n0 + wc * 64 + ni * 16 + col0;
#pragma unroll
      for (int rr = 0; rr < 4; ++rr) {
        int mrow = m0 + wr * 64 + mi * 16 + row0 + rr;
        Cb[(size_t)mrow * ldc + n] = (_Float16)acc[mi][ni][rr];
      }
    }
  }
}

// GEMM2: split-K, 128x256 tile, 8 waves, fp16 partials, BK=64 (two halves).
__global__ __launch_bounds__(512) void k_gemm2(
    const _Float16* __restrict__ A, const _Float16* __restrict__ Bm,
    _Float16* __restrict__ Cm, int lda, int ldb, int ldc,
    long long sA, long long sB, long long sC) {
  __shared__ _Float16 As[2][128 * 32];
  __shared__ _Float16 Bs[2][256 * 32];
  int z = blockIdx.z;
  int b = z / NSPLIT, s = z % NSPLIT;
  int kbeg = s * KCHUNK;
  int klen = min(KCHUNK, LP - kbeg);
  const _Float16* Ab = A + b * sA + (size_t)kbeg;
  const _Float16* Bb = Bm + b * sB + (size_t)kbeg;
  _Float16* Cb = Cm + z * sC;
  int m0 = blockIdx.y * 128, n0 = blockIdx.x * 256;
  int t = threadIdx.x;
  int lane = t & 63, wid = t >> 6;
  int wr = wid >> 2, wc = wid & 3;   // 2 x 4 wave grid, each wave 64x64
  f32x4 acc[4][4] = {};
  for (int k0 = 0; k0 < klen; k0 += 64) {
#pragma unroll
    for (int h = 0; h < 2; ++h) {
      {
        int e = t;                    // A: 512 chunks of 8 fp16
        int r = e >> 2, c = e & 3;
        GLOAD_LDS16(Ab + (size_t)(m0 + r) * lda + k0 + h * 32 + c * 8, As[h] + (size_t)e * 8);
      }
#pragma unroll
      for (int i = 0; i < 2; ++i) {   // B: 1024 chunks
        int e = i * 512 + t;
        int r = e >> 2, c = e & 3;
        GLOAD_LDS16(Bb + (size_t)(n0 + r) * ldb + k0 + h * 32 + c * 8, Bs[h] + (size_t)e * 8);
      }
    }
    __syncthreads();
    int rla = (wr * 64 + (lane & 15)) * 32 + (lane >> 4) * 8;
    int rlb = (wc * 64 + (lane & 15)) * 32 + (lane >> 4) * 8;
#pragma unroll
    for (int h = 0; h < 2; ++h) {
      f16x8 af[4], bf[4];
#pragma unroll
      for (int mi = 0; mi < 4; ++mi) af[mi] = *(const f16x8*)&As[h][rla + mi * 16 * 32];
#pragma unroll
      for (int ni = 0; ni < 4; ++ni) bf[ni] = *(const f16x8*)&Bs[h][rlb + ni * 16 * 32];
#pragma unroll
      for (int mi = 0; mi < 4; ++mi)
#pragma unroll
        for (int ni = 0; ni < 4; ++ni)
          acc[mi][ni] = __builtin_amdgcn_mfma_f32_16x16x32_f16(af[mi], bf[ni], acc[mi][ni], 0, 0, 0);
    }
    __syncthreads();
  }
  int col0 = lane & 15;
  int row0 = (lane >> 4) * 4;
#pragma unroll
  for (int mi = 0; mi < 4; ++mi) {
#pragma unroll
    for (int ni = 0; ni < 4; ++ni) {
      int n = n0 + wc * 64 + ni * 16 + col0;
#pragma unroll
      for (int rr = 0; rr < 4; ++rr) {
        int mrow = m0 + wr * 64 + mi * 16 + row0 + rr;
        Cb[(size_t)mrow * ldc + n] = (_Float16)acc[mi][ni][rr];
      }
    }
  }
}

// fp16 in/out, in-place softmax over l<LTOT of each LP row; pad cols -> 0
__global__ void k_softmax16(_Float16* __restrict__ S) {
  __shared__ float buf[LTOT];
  __shared__ float red[256];
  size_t row = blockIdx.x;
  _Float16* r = S + row * LP;
  f16x8* r8 = (f16x8*)r;
  int tid = threadIdx.x;
  float mx = -1e30f;
  for (int ch = tid; ch < LP / 8; ch += 256) {
    f16x8 v = r8[ch];
    int base = ch * 8;
#pragma unroll
    for (int j = 0; j < 8; ++j) {
      int l = base + j;
      if (l < LTOT) {
        float f = (float)v[j];
        buf[l] = f;
        mx = fmaxf(mx, f);
      }
    }
  }
  red[tid] = mx;
  __syncthreads();
  for (int st = 128; st > 0; st >>= 1) {
    if (tid < st) red[tid] = fmaxf(red[tid], red[tid + st]);
    __syncthreads();
  }
  mx = red[0];
  __syncthreads();
  float sm = 0.f;
  for (int i = tid; i < LTOT; i += 256) {
    float e = __expf(buf[i] - mx);
    buf[i] = e;
    sm += e;
  }
  red[tid] = sm;
  __syncthreads();
  for (int st = 128; st > 0; st >>= 1) {
    if (tid < st) red[tid] += red[tid + st];
    __syncthreads();
  }
  float inv = 1.f / red[0];
  __syncthreads();
  for (int ch = tid; ch < LP / 8; ch += 256) {
    int base = ch * 8;
    f16x8 o;
#pragma unroll
    for (int j = 0; j < 8; ++j) {
      int l = base + j;
      o[j] = (l < LTOT) ? (_Float16)(buf[l] * inv) : (_Float16)0.f;
    }
    r8[ch] = o;
  }
}

// coalesced: cd fastest. G[b, p0+p, cd<450] = sum_s fp16 Gp[(b*NSPLIT+s), p, cd]
__global__ void k_reduceG(const _Float16* __restrict__ Gp, float* __restrict__ G,
                          int pc, int p0) {
  int t = blockIdx.x * blockDim.x + threadIdx.x;
  int total = NB * pc * CD;
  if (t >= total) return;
  int cd = t % CD;
  int p = (t / CD) % pc;
  int b = t / (CD * pc);
  float acc = 0.f;
#pragma unroll
  for (int s = 0; s < NSPLIT; ++s)
    acc += (float)Gp[(((size_t)(b * NSPLIT + s) * pc) + p) * CDP + cd];
  G[((size_t)b * HW0 + p0 + p) * CD + cd] = acc;
}

__global__ void k_final(const float* __restrict__ G, const float* __restrict__ x,
                        float* __restrict__ out) {
  int t = blockIdx.x * blockDim.x + threadIdx.x;
  int total = NB * NC * HW0;
  if (t >= total) return;
  int p = t % HW0;
  int c = (t / HW0) % NC;
  int b = t / (HW0 * NC);
  int i = p / W0, j = p % W0;
  float sum = 0.f;
#pragma unroll
  for (int kh = 0; kh < 3; ++kh) {
    int pi = i - kh + 1;
    if (pi < 0 || pi >= H0) continue;
#pragma unroll
    for (int kw = 0; kw < 3; ++kw) {
      int pj = j - kw + 1;
      if (pj < 0 || pj >= W0) continue;
      sum += G[((size_t)b * HW0 + pi * W0 + pj) * CD + c * 9 + kh * 3 + kw];
    }
  }
  out[t] = sum + x[t];
}

static inline size_t rup(size_t x) { return (x + 255) & ~(size_t)255; }

extern "C" void kernel_launch(void* const* d_in, const int* in_sizes, int n_in,
                              void* d_out, int out_size, void* d_ws, size_t ws_size,
                              hipStream_t stream) {
  const float* x   = (const float*)d_in[0];
  const float* Wmb = (const float*)d_in[1];
  const float* bmb = (const float*)d_in[2];
  const float* amb = (const float*)d_in[3];
  const float* Wm  = (const float*)d_in[4];
  const float* bm  = (const float*)d_in[5];
  const float* am  = (const float*)d_in[6];
  const float* Wa  = (const float*)d_in[7];
  const float* ba  = (const float*)d_in[8];
  const float* aa  = (const float*)d_in[9];
  float* out = (float*)d_out;
  char* ws = (char*)d_ws;

  size_t off = 0;
  float* mb    = (float*)(ws + off); off = rup(off + sizeof(float) * NB * NCR * HW0);
  float* refs  = (float*)(ws + off); off = rup(off + sizeof(float) * NB * NC * LTOT);
  float* base  = (float*)(ws + off); off = rup(off + sizeof(float) * NB * NC * LTOT);
  float* m     = (float*)(ws + off); off = rup(off + sizeof(float) * NB * NCR * LTOT);
  _Float16* xq16 = (_Float16*)(ws + off); off = rup(off + sizeof(_Float16) * NB * HW0 * KP);
  _Float16* wn16 = (_Float16*)(ws + off); off = rup(off + sizeof(_Float16) * (size_t)NB * LP * KP);
  _Float16* bt16 = (_Float16*)(ws + off); off = rup(off + sizeof(_Float16) * (size_t)NB * CDP * LP);
  float* G     = (float*)(ws + off); off = rup(off + sizeof(float) * NB * HW0 * CD);

  // per-chunk: scores/attn fp16 [NB][pc][LP] + Gp fp16 [NB*NSPLIT][pc][CDP]
  int pc = HW0;
  {
    size_t avail = (ws_size > off) ? ws_size - off - 1024 : 0;
    size_t per = (size_t)NB * (LP * 2 + NSPLIT * CDP * 2);
    while (pc > 128 && (size_t)pc * per > avail) {
      if (pc == HW0) pc = 1152;
      else if (pc == 1152) pc = 768;
      else if (pc == 768) pc = 384;
      else pc = 128;
    }
  }
  _Float16* scbuf16 = (_Float16*)(ws + off); off = rup(off + sizeof(_Float16) * (size_t)NB * pc * LP);
  _Float16* Gp = (_Float16*)(ws + off);

  const int th = 256;
  k_conv1x1<<<(NB * NCR * HW0 + th - 1) / th, th, 0, stream>>>(x, Wmb, bmb, amb, mb, NC, NCR, HW0);
  k_build_refs<<<(NB * NC * LTOT + th - 1) / th, th, 0, stream>>>(x, refs);
  k_conv_bm<<<(NB * (NC + NCR) * LTOT + th - 1) / th, th, 0, stream>>>(
      refs, Wa, ba, aa, Wm, bm, am, base, m);
  k_build_xq<<<NB * HW0, 256, 0, stream>>>(mb, xq16);
  k_build_wn<<<NB * LP / 4, 256, 0, stream>>>(m, wn16);
  k_build_brawT<<<(NB * CDP * LP + th - 1) / th, th, 0, stream>>>(base, bt16);

  for (int p0 = 0; p0 < HW0; p0 += pc) {
    // scores fp16: [b, p, l] = xq . wn
    dim3 g1(LP / 128, pc / 128, NB);
    k_gemm_nt_f16<<<g1, 256, 0, stream>>>(
        xq16 + (size_t)p0 * KP, wn16, scbuf16,
        KP, KP, KP, LP,
        (long long)HW0 * KP, (long long)LP * KP, (long long)pc * LP);
    // softmax in place (fp16 -> fp16 attn)
    k_softmax16<<<NB * pc, 256, 0, stream>>>(scbuf16);
    // Gp[(b,s), p, cd] = attn(chunk s) . BrawT(chunk s); 128x256 tile, 8 waves
    dim3 g2(CDP / 256, pc / 128, NB * NSPLIT);
    k_gemm2<<<g2, 512, 0, stream>>>(
        scbuf16, bt16, Gp,
        LP, LP, CDP,
        (long long)pc * LP, (long long)CDP * LP, (long long)pc * CDP);
    // coalesced split-reduce into G
    k_reduceG<<<(NB * pc * CD + th - 1) / th, th, 0, stream>>>(Gp, G, pc, p0);
  }
  k_final<<<(NB * NC * HW0 + th - 1) / th, th, 0, stream>>>(G, x, out);
}

// Round 14
// 273.002 us; speedup vs baseline: 1.1538x; 1.1088x over previous
//
#include <hip/hip_runtime.h>
#include <math.h>

#define NB 2
#define NC 50
#define NCR 25
#define H0 48
#define W0 48
#define HW0 2304
#define LTOT 7470
#define LP 7552      // LTOT padded to 128
#define K225 225
#define KP 256       // 225 padded to 256
#define CD 450       // C*9
#define CDP 512      // padded to 128
#define NSPLIT 12
#define KCHUNK 640   // 11*640 + 512 = 7552; both 640 and 512 are %64 == 0

typedef _Float16 f16x8 __attribute__((ext_vector_type(8)));
typedef float f32x4 __attribute__((ext_vector_type(4)));

#define GLOAD_LDS16(gp, lp) __builtin_amdgcn_global_load_lds( \
    (const __attribute__((address_space(1))) void*)(gp),      \
    (__attribute__((address_space(3))) void*)(lp), 16, 0, 0)

__device__ __forceinline__ void decode_pix(int pix, int& s, int& off, int& d) {
  if (pix < 2304)      { s = 0; off = 0;    d = 48; }
  else if (pix < 4153) { s = 1; off = 2304; d = 43; }
  else if (pix < 5597) { s = 2; off = 4153; d = 38; }
  else if (pix < 6686) { s = 3; off = 5597; d = 33; }
  else                 { s = 4; off = 6686; d = 28; }
}

__device__ __forceinline__ float cubw(float t) {
  const float a = -0.75f;
  float at = fabsf(t);
  float w1 = ((a + 2.f) * at - (a + 3.f)) * at * at + 1.f;
  float w2 = (((at - 5.f) * at + 8.f) * at - 4.f) * a;
  return at <= 1.f ? w1 : (at < 2.f ? w2 : 0.f);
}

// merged prep 1: [0, NBLK_MB) -> conv1x1 producing mb; rest -> build_refs
#define NBLK_MB ((NB * NCR * HW0 + 255) / 256)     // 450
#define NBLK_REFS ((NB * NC * LTOT + 255) / 256)   // 2918
__global__ void k_prep1(const float* __restrict__ x,
                        const float* __restrict__ Wmb, const float* __restrict__ bmb,
                        const float* __restrict__ amb,
                        float* __restrict__ mb, float* __restrict__ refs) {
  if (blockIdx.x < NBLK_MB) {
    int t = blockIdx.x * 256 + threadIdx.x;
    if (t >= NB * NCR * HW0) return;
    int pix = t % HW0;
    int o = (t / HW0) % NCR;
    int b = t / (HW0 * NCR);
    float acc = bmb[o];
    const float* ip = x + (size_t)b * NC * HW0 + pix;
    const float* wr = Wmb + o * NC;
    for (int c = 0; c < NC; ++c) acc = fmaf(wr[c], ip[(size_t)c * HW0], acc);
    float a = amb[0];
    mb[t] = acc >= 0.f ? acc : a * acc;
    return;
  }
  int t = (blockIdx.x - NBLK_MB) * 256 + threadIdx.x;
  if (t >= NB * NC * LTOT) return;
  int pix = t % LTOT;
  int c = (t / LTOT) % NC;
  int b = t / (LTOT * NC);
  int s, off, d;
  decode_pix(pix, s, off, d);
  float v;
  const float* xb = x + ((size_t)b * NC + c) * HW0;
  if (s == 0) {
    v = xb[pix];
  } else {
    int rem = pix - off;
    int oy = rem / d, ox = rem % d;
    float scale = 47.f / (float)(d - 1);
    float sy = oy * scale, sx = ox * scale;
    float fy0 = floorf(sy), fx0 = floorf(sx);
    int iy = (int)fy0, ix = (int)fx0;
    float fy = sy - fy0, fx = sx - fx0;
    float wy[4], wx[4];
#pragma unroll
    for (int dd = 0; dd < 4; ++dd) {
      wy[dd] = cubw(fy - (float)(dd - 1));
      wx[dd] = cubw(fx - (float)(dd - 1));
    }
    float acc = 0.f;
#pragma unroll
    for (int p = 0; p < 4; ++p) {
      int yy = min(max(iy + p - 1, 0), 47);
      float rowacc = 0.f;
#pragma unroll
      for (int q = 0; q < 4; ++q) {
        int xx = min(max(ix + q - 1, 0), 47);
        rowacc = fmaf(wx[q], xb[yy * 48 + xx], rowacc);
      }
      acc = fmaf(wy[p], rowacc, acc);
    }
    v = acc;
  }
  refs[t] = v;
}

// fused: base (50 ch, Wa) and m (25 ch, Wm) from refs, one pass
__global__ void k_conv_bm(const float* __restrict__ refs,
                          const float* __restrict__ Wa, const float* __restrict__ ba,
                          const float* __restrict__ aa,
                          const float* __restrict__ Wm, const float* __restrict__ bm,
                          const float* __restrict__ am,
                          float* __restrict__ base, float* __restrict__ m) {
  int t = blockIdx.x * blockDim.x + threadIdx.x;
  int total = NB * (NC + NCR) * LTOT;
  if (t >= total) return;
  int pix = t % LTOT;
  int o = (t / LTOT) % (NC + NCR);
  int b = t / (LTOT * (NC + NCR));
  const float* ip = refs + (size_t)b * NC * LTOT + pix;
  const float* wr;
  float acc, a;
  float* dst;
  if (o < NC) {
    wr = Wa + o * NC; acc = ba[o]; a = aa[0];
    dst = base + ((size_t)b * NC + o) * LTOT + pix;
  } else {
    int o2 = o - NC;
    wr = Wm + o2 * NC; acc = bm[o2]; a = am[0];
    dst = m + ((size_t)b * NCR + o2) * LTOT + pix;
  }
  for (int c = 0; c < NC; ++c) acc = fmaf(wr[c], ip[(size_t)c * LTOT], acc);
  *dst = acc >= 0.f ? acc : a * acc;
}

// merged prep 3: xq blocks, then wn wave-blocks, then brawT blocks
#define NBLK_XQ (NB * HW0)              // 4608
#define NBLK_WN (NB * LP / 4)           // 3776
#define NBLK_BT (NB * CDP * LP / 256)   // 30208
__global__ void k_prep3(const float* __restrict__ mb, const float* __restrict__ m,
                        const float* __restrict__ base,
                        _Float16* __restrict__ xq, _Float16* __restrict__ wn,
                        _Float16* __restrict__ BT) {
  int blk = blockIdx.x;
  if (blk < NBLK_XQ) {
    int bp = blk;
    int b = bp / HW0, p = bp % HW0;
    int i = p / W0, j = p % W0;
    int k = threadIdx.x;
    float v = 0.f;
    if (k < K225) {
      int c = k / 9, r = k % 9, di = r / 3, dj = r % 3;
      int yy = i + di - 1, xx = j + dj - 1;
      if (yy >= 0 && yy < H0 && xx >= 0 && xx < W0)
        v = mb[((size_t)b * NCR + c) * HW0 + yy * W0 + xx];
    }
    xq[(size_t)bp * KP + k] = (_Float16)v;
    return;
  }
  blk -= NBLK_XQ;
  if (blk < NBLK_WN) {
    int gw = blk * 4 + (threadIdx.x >> 6);
    int lane = threadIdx.x & 63;
    int b = gw / LP, l = gw % LP;
    float v[4] = {0.f, 0.f, 0.f, 0.f};
    float ss = 0.f;
    if (l < LTOT) {
      int s, off, d;
      decode_pix(l, s, off, d);
      int rem = l - off;
      int y = rem / d, x = rem % d;
#pragma unroll
      for (int j = 0; j < 4; ++j) {
        int k = lane + 64 * j;
        if (k < K225) {
          int c = k / 9, r = k % 9, di = r / 3, dj = r % 3;
          int yy = y + di - 1, xx = x + dj - 1;
          if (yy >= 0 && yy < d && xx >= 0 && xx < d)
            v[j] = m[((size_t)b * NCR + c) * LTOT + off + yy * d + xx];
        }
        ss = fmaf(v[j], v[j], ss);
      }
    }
#pragma unroll
    for (int o = 1; o < 64; o <<= 1) ss += __shfl_xor(ss, o);
    float sc = 10.f / fmaxf(sqrtf(ss), 1e-4f);
#pragma unroll
    for (int j = 0; j < 4; ++j) {
      int k = lane + 64 * j;
      wn[(size_t)gw * KP + k] = (l < LTOT) ? (_Float16)(v[j] * sc) : (_Float16)0.f;
    }
    return;
  }
  blk -= NBLK_WN;
  int t = blk * 256 + threadIdx.x;
  int l = t % LP;
  int cd = (t / LP) % CDP;
  int b = t / (LP * CDP);
  float v = 0.f;
  if (cd < CD && l < LTOT) {
    int s, off, d;
    decode_pix(l, s, off, d);
    int rem = l - off;
    int y = rem / d, x = rem % d;
    int c = cd / 9, r = cd % 9, di = r / 3, dj = r % 3;
    int yy = y + di - 1, xx = x + dj - 1;
    if (yy >= 0 && yy < d && xx >= 0 && xx < d)
      v = 0.25f * base[((size_t)b * NC + c) * LTOT + off + yy * d + xx];
  }
  BT[t] = (_Float16)v;
}

// GEMM1: C[m,n] = sum_k A[m,k]*B[n,k], 128x128 tile, 4 waves, fp16 out, BK=64.
__global__ __launch_bounds__(256) void k_gemm_nt_f16(
    const _Float16* __restrict__ A, const _Float16* __restrict__ Bm,
    _Float16* __restrict__ Cm, int K, int lda, int ldb, int ldc,
    long long sA, long long sB, long long sC) {
  __shared__ _Float16 As[2][128 * 32];   // [khalf][row*32+col]
  __shared__ _Float16 Bs[2][128 * 32];
  const _Float16* Ab = A + blockIdx.z * sA;
  const _Float16* Bb = Bm + blockIdx.z * sB;
  _Float16* Cb = Cm + blockIdx.z * sC;
  int m0 = blockIdx.y * 128, n0 = blockIdx.x * 128;
  int t = threadIdx.x;
  int lane = t & 63, wid = t >> 6;
  int wr = wid >> 1, wc = wid & 1;
  f32x4 acc[4][4] = {};
  for (int k0 = 0; k0 < K; k0 += 64) {
#pragma unroll
    for (int h = 0; h < 2; ++h) {
#pragma unroll
      for (int i = 0; i < 2; ++i) {
        int e = i * 256 + t;
        int r = e >> 2, c = e & 3;
        GLOAD_LDS16(Ab + (size_t)(m0 + r) * lda + k0 + h * 32 + c * 8, As[h] + (size_t)e * 8);
        GLOAD_LDS16(Bb + (size_t)(n0 + r) * ldb + k0 + h * 32 + c * 8, Bs[h] + (size_t)e * 8);
      }
    }
    __syncthreads();
    int rla = (wr * 64 + (lane & 15)) * 32 + (lane >> 4) * 8;
    int rlb = (wc * 64 + (lane & 15)) * 32 + (lane >> 4) * 8;
#pragma unroll
    for (int h = 0; h < 2; ++h) {
      f16x8 af[4], bf[4];
#pragma unroll
      for (int mi = 0; mi < 4; ++mi) af[mi] = *(const f16x8*)&As[h][rla + mi * 16 * 32];
#pragma unroll
      for (int ni = 0; ni < 4; ++ni) bf[ni] = *(const f16x8*)&Bs[h][rlb + ni * 16 * 32];
#pragma unroll
      for (int mi = 0; mi < 4; ++mi)
#pragma unroll
        for (int ni = 0; ni < 4; ++ni)
          acc[mi][ni] = __builtin_amdgcn_mfma_f32_16x16x32_f16(af[mi], bf[ni], acc[mi][ni], 0, 0, 0);
    }
    __syncthreads();
  }
  int col0 = lane & 15;
  int row0 = (lane >> 4) * 4;
#pragma unroll
  for (int mi = 0; mi < 4; ++mi) {
#pragma unroll
    for (int ni = 0; ni < 4; ++ni) {
      int n = n0 + wc * 64 + ni * 16 + col0;
#pragma unroll
      for (int rr = 0; rr < 4; ++rr) {
        int mrow = m0 + wr * 64 + mi * 16 + row0 + rr;
        Cb[(size_t)mrow * ldc + n] = (_Float16)acc[mi][ni][rr];
      }
    }
  }
}

// GEMM2: split-K (12 chunks), 128x256 tile, 8 waves, fp16 partials, BK=64.
// C-write guarded to n < CD (pad cols never read by reduceG).
__global__ __launch_bounds__(512) void k_gemm2(
    const _Float16* __restrict__ A, const _Float16* __restrict__ Bm,
    _Float16* __restrict__ Cm, int lda, int ldb, int ldc,
    long long sA, long long sB, long long sC) {
  __shared__ _Float16 As[2][128 * 32];
  __shared__ _Float16 Bs[2][256 * 32];
  int z = blockIdx.z;
  int b = z / NSPLIT, s = z % NSPLIT;
  int kbeg = s * KCHUNK;
  int klen = min(KCHUNK, LP - kbeg);
  const _Float16* Ab = A + b * sA + (size_t)kbeg;
  const _Float16* Bb = Bm + b * sB + (size_t)kbeg;
  _Float16* Cb = Cm + z * sC;
  int m0 = blockIdx.y * 128, n0 = blockIdx.x * 256;
  int t = threadIdx.x;
  int lane = t & 63, wid = t >> 6;
  int wr = wid >> 2, wc = wid & 3;   // 2 x 4 wave grid, each wave 64x64
  f32x4 acc[4][4] = {};
  for (int k0 = 0; k0 < klen; k0 += 64) {
#pragma unroll
    for (int h = 0; h < 2; ++h) {
      {
        int e = t;                    // A: 512 chunks of 8 fp16
        int r = e >> 2, c = e & 3;
        GLOAD_LDS16(Ab + (size_t)(m0 + r) * lda + k0 + h * 32 + c * 8, As[h] + (size_t)e * 8);
      }
#pragma unroll
      for (int i = 0; i < 2; ++i) {   // B: 1024 chunks
        int e = i * 512 + t;
        int r = e >> 2, c = e & 3;
        GLOAD_LDS16(Bb + (size_t)(n0 + r) * ldb + k0 + h * 32 + c * 8, Bs[h] + (size_t)e * 8);
      }
    }
    __syncthreads();
    int rla = (wr * 64 + (lane & 15)) * 32 + (lane >> 4) * 8;
    int rlb = (wc * 64 + (lane & 15)) * 32 + (lane >> 4) * 8;
#pragma unroll
    for (int h = 0; h < 2; ++h) {
      f16x8 af[4], bf[4];
#pragma unroll
      for (int mi = 0; mi < 4; ++mi) af[mi] = *(const f16x8*)&As[h][rla + mi * 16 * 32];
#pragma unroll
      for (int ni = 0; ni < 4; ++ni) bf[ni] = *(const f16x8*)&Bs[h][rlb + ni * 16 * 32];
#pragma unroll
      for (int mi = 0; mi < 4; ++mi)
#pragma unroll
        for (int ni = 0; ni < 4; ++ni)
          acc[mi][ni] = __builtin_amdgcn_mfma_f32_16x16x32_f16(af[mi], bf[ni], acc[mi][ni], 0, 0, 0);
    }
    __syncthreads();
  }
  int col0 = lane & 15;
  int row0 = (lane >> 4) * 4;
#pragma unroll
  for (int mi = 0; mi < 4; ++mi) {
#pragma unroll
    for (int ni = 0; ni < 4; ++ni) {
      int n = n0 + wc * 64 + ni * 16 + col0;
      if (n >= CD) continue;
#pragma unroll
      for (int rr = 0; rr < 4; ++rr) {
        int mrow = m0 + wr * 64 + mi * 16 + row0 + rr;
        Cb[(size_t)mrow * ldc + n] = (_Float16)acc[mi][ni][rr];
      }
    }
  }
}

// fp16 in/out, in-place softmax over l<LTOT of each LP row; pad cols -> 0
__global__ void k_softmax16(_Float16* __restrict__ S) {
  __shared__ float buf[LTOT];
  __shared__ float red[256];
  size_t row = blockIdx.x;
  _Float16* r = S + row * LP;
  f16x8* r8 = (f16x8*)r;
  int tid = threadIdx.x;
  float mx = -1e30f;
  for (int ch = tid; ch < LP / 8; ch += 256) {
    f16x8 v = r8[ch];
    int base = ch * 8;
#pragma unroll
    for (int j = 0; j < 8; ++j) {
      int l = base + j;
      if (l < LTOT) {
        float f = (float)v[j];
        buf[l] = f;
        mx = fmaxf(mx, f);
      }
    }
  }
  red[tid] = mx;
  __syncthreads();
  for (int st = 128; st > 0; st >>= 1) {
    if (tid < st) red[tid] = fmaxf(red[tid], red[tid + st]);
    __syncthreads();
  }
  mx = red[0];
  __syncthreads();
  float sm = 0.f;
  for (int i = tid; i < LTOT; i += 256) {
    float e = __expf(buf[i] - mx);
    buf[i] = e;
    sm += e;
  }
  red[tid] = sm;
  __syncthreads();
  for (int st = 128; st > 0; st >>= 1) {
    if (tid < st) red[tid] += red[tid + st];
    __syncthreads();
  }
  float inv = 1.f / red[0];
  __syncthreads();
  for (int ch = tid; ch < LP / 8; ch += 256) {
    int base = ch * 8;
    f16x8 o;
#pragma unroll
    for (int j = 0; j < 8; ++j) {
      int l = base + j;
      o[j] = (l < LTOT) ? (_Float16)(buf[l] * inv) : (_Float16)0.f;
    }
    r8[ch] = o;
  }
}

// coalesced: cd fastest. G[b, p0+p, cd<450] = sum_s fp16 Gp[(b*NSPLIT+s), p, cd]
__global__ void k_reduceG(const _Float16* __restrict__ Gp, float* __restrict__ G,
                          int pc, int p0) {
  int t = blockIdx.x * blockDim.x + threadIdx.x;
  int total = NB * pc * CD;
  if (t >= total) return;
  int cd = t % CD;
  int p = (t / CD) % pc;
  int b = t / (CD * pc);
  float acc = 0.f;
#pragma unroll
  for (int s = 0; s < NSPLIT; ++s)
    acc += (float)Gp[(((size_t)(b * NSPLIT + s) * pc) + p) * CDP + cd];
  G[((size_t)b * HW0 + p0 + p) * CD + cd] = acc;
}

__global__ void k_final(const float* __restrict__ G, const float* __restrict__ x,
                        float* __restrict__ out) {
  int t = blockIdx.x * blockDim.x + threadIdx.x;
  int total = NB * NC * HW0;
  if (t >= total) return;
  int p = t % HW0;
  int c = (t / HW0) % NC;
  int b = t / (HW0 * NC);
  int i = p / W0, j = p % W0;
  float sum = 0.f;
#pragma unroll
  for (int kh = 0; kh < 3; ++kh) {
    int pi = i - kh + 1;
    if (pi < 0 || pi >= H0) continue;
#pragma unroll
    for (int kw = 0; kw < 3; ++kw) {
      int pj = j - kw + 1;
      if (pj < 0 || pj >= W0) continue;
      sum += G[((size_t)b * HW0 + pi * W0 + pj) * CD + c * 9 + kh * 3 + kw];
    }
  }
  out[t] = sum + x[t];
}

static inline size_t rup(size_t x) { return (x + 255) & ~(size_t)255; }

extern "C" void kernel_launch(void* const* d_in, const int* in_sizes, int n_in,
                              void* d_out, int out_size, void* d_ws, size_t ws_size,
                              hipStream_t stream) {
  const float* x   = (const float*)d_in[0];
  const float* Wmb = (const float*)d_in[1];
  const float* bmb = (const float*)d_in[2];
  const float* amb = (const float*)d_in[3];
  const float* Wm  = (const float*)d_in[4];
  const float* bm  = (const float*)d_in[5];
  const float* am  = (const float*)d_in[6];
  const float* Wa  = (const float*)d_in[7];
  const float* ba  = (const float*)d_in[8];
  const float* aa  = (const float*)d_in[9];
  float* out = (float*)d_out;
  char* ws = (char*)d_ws;

  size_t off = 0;
  float* mb    = (float*)(ws + off); off = rup(off + sizeof(float) * NB * NCR * HW0);
  float* refs  = (float*)(ws + off); off = rup(off + sizeof(float) * NB * NC * LTOT);
  float* base  = (float*)(ws + off); off = rup(off + sizeof(float) * NB * NC * LTOT);
  float* m     = (float*)(ws + off); off = rup(off + sizeof(float) * NB * NCR * LTOT);
  _Float16* xq16 = (_Float16*)(ws + off); off = rup(off + sizeof(_Float16) * NB * HW0 * KP);
  _Float16* wn16 = (_Float16*)(ws + off); off = rup(off + sizeof(_Float16) * (size_t)NB * LP * KP);
  _Float16* bt16 = (_Float16*)(ws + off); off = rup(off + sizeof(_Float16) * (size_t)NB * CDP * LP);
  float* G     = (float*)(ws + off); off = rup(off + sizeof(float) * NB * HW0 * CD);

  // per-chunk: scores/attn fp16 [NB][pc][LP] + Gp fp16 [NB*NSPLIT][pc][CDP]
  int pc = HW0;
  {
    size_t avail = (ws_size > off) ? ws_size - off - 1024 : 0;
    size_t per = (size_t)NB * (LP * 2 + NSPLIT * CDP * 2);
    while (pc > 128 && (size_t)pc * per > avail) {
      if (pc == HW0) pc = 1152;
      else if (pc == 1152) pc = 768;
      else if (pc == 768) pc = 384;
      else pc = 128;
    }
  }
  _Float16* scbuf16 = (_Float16*)(ws + off); off = rup(off + sizeof(_Float16) * (size_t)NB * pc * LP);
  _Float16* Gp = (_Float16*)(ws + off);

  const int th = 256;
  k_prep1<<<NBLK_MB + NBLK_REFS, 256, 0, stream>>>(x, Wmb, bmb, amb, mb, refs);
  k_conv_bm<<<(NB * (NC + NCR) * LTOT + th - 1) / th, th, 0, stream>>>(
      refs, Wa, ba, aa, Wm, bm, am, base, m);
  k_prep3<<<NBLK_XQ + NBLK_WN + NBLK_BT, 256, 0, stream>>>(mb, m, base, xq16, wn16, bt16);

  for (int p0 = 0; p0 < HW0; p0 += pc) {
    // scores fp16: [b, p, l] = xq . wn
    dim3 g1(LP / 128, pc / 128, NB);
    k_gemm_nt_f16<<<g1, 256, 0, stream>>>(
        xq16 + (size_t)p0 * KP, wn16, scbuf16,
        KP, KP, KP, LP,
        (long long)HW0 * KP, (long long)LP * KP, (long long)pc * LP);
    // softmax in place (fp16 -> fp16 attn)
    k_softmax16<<<NB * pc, 256, 0, stream>>>(scbuf16);
    // Gp[(b,s), p, cd] = attn(chunk s) . BrawT(chunk s); 128x256 tile, 8 waves
    dim3 g2(CDP / 256, pc / 128, NB * NSPLIT);
    k_gemm2<<<g2, 512, 0, stream>>>(
        scbuf16, bt16, Gp,
        LP, LP, CDP,
        (long long)pc * LP, (long long)CDP * LP, (long long)pc * CDP);
    // coalesced split-reduce into G
    k_reduceG<<<(NB * pc * CD + th - 1) / th, th, 0, stream>>>(Gp, G, pc, p0);
  }
  k_final<<<(NB * NC * HW0 + th - 1) / th, th, 0, stream>>>(G, x, out);
}